// Round 8
// baseline (198.949 us; speedup 1.0000x reference)
//
#include <hip/hip_runtime.h>
#include <cstdint>
#include <cstddef>

// x (B=8, C=64, S=32768) fp32; codebook (512, 64) fp32.
#define SPATIAL   32768
#define CHANNELS  64
#define NUM_EMB   512
#define NPOS      262144
#define OUT_ELEMS 16777216
#define BLOCK     256            // 4 waves
#define POSB      128            // positions per block (2 waves share a 64-pos group)
#define LOSS_SCALE (1.25f / 16777216.0f)

typedef __attribute__((ext_vector_type(8))) short bf16x8;
typedef __attribute__((ext_vector_type(4))) float f32x4;

union b8u { int i[4]; bf16x8 v; };
union fiu { float f; unsigned u; };

// fp32 -> bf16 RNE (prep only)
__device__ __forceinline__ short f2bf_rne(float f) {
    fiu v; v.f = f;
    unsigned r = v.u + 0x7fffu + ((v.u >> 16) & 1u);
    return (short)(r >> 16);
}

// Prep: cbbf = bf16(codebook), cbn[e] = -0.5*||cb_e||^2, zero loss slot.
__global__ void vq_prep(const float* __restrict__ cb,
                        short* __restrict__ cbbf,
                        float* __restrict__ cbn,
                        float* __restrict__ loss_slot) {
    int e = blockIdx.x * blockDim.x + threadIdx.x;
    if (e == 0) *loss_slot = 0.0f;
    if (e < NUM_EMB) {
        float s = 0.0f;
#pragma unroll
        for (int c = 0; c < CHANNELS; ++c) {
            float v = cb[e * CHANNELS + c];
            cbbf[e * CHANNELS + c] = f2bf_rne(v);
            s = __builtin_fmaf(v, v, s);
        }
        cbn[e] = -0.5f * s;
    }
}

// R8 = R6's inner-loop shape (loads at top of body, compiler-scheduled, no
// manual prefetch -- R7's prefetch blew VGPR 56->180 and halved occupancy)
// + wave-split codebook: each wave scans 256 entries for 64 positions,
// halves merged by packed-float max in LDS. 8192 waves -> 32 waves/CU.
__global__ __launch_bounds__(BLOCK) void vq_main(
    const float* __restrict__ x,
    const float* __restrict__ cb,
    const short* __restrict__ cbbf,
    const float* __restrict__ cbn,
    float* __restrict__ out,
    float* __restrict__ loss_slot) {
#pragma clang fp contract(off)
    __shared__ float pm[2][POSB];   // packed (score|511-e) max per half per position
    __shared__ float wsum[4];

    const int tid  = threadIdx.x;
    const int wave = tid >> 6, lane = tid & 63;
    const int q    = lane >> 4, col = lane & 15;
    const int posgrp = wave >> 1;          // which 64-position group
    const int half   = wave & 1;           // which codebook half

    const int blockPos = blockIdx.x * POSB;   // 128 | 32768 -> whole block same b
    const int b     = blockPos >> 15;
    const int sbase = blockPos & 32767;
    const float* xb = x + (size_t)b * (CHANNELS * SPATIAL);
    const int wposbase = sbase + posgrp * 64;

    // ---- A fragments: 64 positions = 4 M-tiles of 16; bf16 by truncation ----
    b8u A[4][2];
#pragma unroll
    for (int t = 0; t < 4; ++t) {
        const unsigned* pu = (const unsigned*)xb + (wposbase + t * 16 + col);
#pragma unroll
        for (int kh = 0; kh < 2; ++kh) {
#pragma unroll
            for (int jj = 0; jj < 4; ++jj) {
                unsigned u0 = pu[(size_t)(kh * 32 + q * 8 + 2 * jj + 0) * SPATIAL];
                unsigned u1 = pu[(size_t)(kh * 32 + q * 8 + 2 * jj + 1) * SPATIAL];
                A[t][kh].i[jj] = __builtin_amdgcn_perm(u1, u0, 0x07060302u);
            }
        }
    }

    // packed running max per (t, r): high 23 bits score, low 9 bits 511-e
    float m[4][4];
#pragma unroll
    for (int t = 0; t < 4; ++t)
#pragma unroll
        for (int r = 0; r < 4; ++r) m[t][r] = -3.4e38f;

    const unsigned MASK = 0xFFFFFE00u;
    const int halfBase = half * 256;

    for (int nt = 0; nt < 16; ++nt) {
        const int e0 = halfBase + nt * 16;
        // B[n=col][k=q*8+j]: entry row e0+col, contiguous bf16 from global (L2-hot)
        const short* brow = cbbf + (size_t)(e0 + col) * CHANNELS + q * 8;
        bf16x8 B0 = *(const bf16x8*)(brow);
        bf16x8 B1 = *(const bf16x8*)(brow + 32);
        float cn = cbn[e0 + col];
        f32x4 ci = {cn, cn, cn, cn};
        const unsigned enc = (unsigned)(511 - (e0 + col));
#pragma unroll
        for (int t = 0; t < 4; ++t) {
            f32x4 acc = __builtin_amdgcn_mfma_f32_16x16x32_bf16(A[t][0].v, B0, ci, 0, 0, 0);
            acc = __builtin_amdgcn_mfma_f32_16x16x32_bf16(A[t][1].v, B1, acc, 0, 0, 0);
#pragma unroll
            for (int r = 0; r < 4; ++r) {
                fiu p; p.f = acc[r];
                p.u = (p.u & MASK) | enc;        // v_and_or_b32
                m[t][r] = fmaxf(m[t][r], p.f);   // v_max_f32
            }
        }
    }

    // ---- cross-lane max per position (butterfly over the 16 cols) ----
#pragma unroll
    for (int t = 0; t < 4; ++t) {
#pragma unroll
        for (int r = 0; r < 4; ++r) {
            float v = m[t][r];
#pragma unroll
            for (int d = 1; d < 16; d <<= 1)
                v = fmaxf(v, __shfl_xor(v, d, 64));
            if (col == 0)
                pm[half][posgrp * 64 + t * 16 + q * 4 + r] = v;
        }
    }
    __syncthreads();   // halves merge across waves

    // ---- epilogue: 2 threads per position, 32 channels each ----
    const int chalf = tid >> 7;          // 0 or 1
    const int pos   = tid & 127;
    fiu pk; pk.f = fmaxf(pm[0][pos], pm[1][pos]);
    const int bidx = 511 - (int)(pk.u & 511u);

    const float* qrow = cb + (size_t)bidx * CHANNELS + chalf * 32;
    const float* px = xb + (sbase + pos) + (size_t)(chalf * 32) * SPATIAL;
    float* op = out + (size_t)b * (CHANNELS * SPATIAL) + (sbase + pos)
                    + (size_t)(chalf * 32) * SPATIAL;
    float lsum = 0.0f;
#pragma unroll
    for (int c = 0; c < 32; ++c) {
        float xv = px[(size_t)c * SPATIAL];
        float t2 = qrow[c] - xv;
        op[(size_t)c * SPATIAL] = xv + t2;
        lsum = __builtin_fmaf(t2, t2, lsum);
    }

    // block loss reduction -> one atomic
#pragma unroll
    for (int off = 32; off > 0; off >>= 1) lsum += __shfl_down(lsum, off, 64);
    if (lane == 0) wsum[wave] = lsum;
    __syncthreads();
    if (tid == 0) {
        float bs = (wsum[0] + wsum[1]) + (wsum[2] + wsum[3]);
        atomicAdd(loss_slot, bs * LOSS_SCALE);
    }
}

extern "C" void kernel_launch(void* const* d_in, const int* in_sizes, int n_in,
                              void* d_out, int out_size, void* d_ws, size_t ws_size,
                              hipStream_t stream) {
    const float* x  = (const float*)d_in[0];
    const float* cb = (const float*)d_in[1];
    float* out = (float*)d_out;
    short* cbbf = (short*)d_ws;                        // 512*64 bf16 = 64 KB
    float* cbn  = (float*)(cbbf + NUM_EMB * CHANNELS); // 512 floats
    float* loss_slot = out + OUT_ELEMS;

    vq_prep<<<2, 256, 0, stream>>>(cb, cbbf, cbn, loss_slot);
    vq_main<<<NPOS / POSB, BLOCK, 0, stream>>>(x, cb, cbbf, cbn, out, loss_slot);
}

// Round 9
// 165.401 us; speedup vs baseline: 1.2028x; 1.2028x over previous
//
#include <hip/hip_runtime.h>
#include <cstdint>
#include <cstddef>

// x (B=8, C=64, S=32768) fp32; codebook (512, 64) fp32.
#define SPATIAL   32768
#define CHANNELS  64
#define NUM_EMB   512
#define NPOS      262144
#define OUT_ELEMS 16777216
#define BLOCK     256            // 4 waves
#define POSB      128            // positions per block (2 waves share a 64-pos group)
#define LOSS_SCALE (1.25f / 16777216.0f)

typedef __attribute__((ext_vector_type(8))) short bf16x8;
typedef __attribute__((ext_vector_type(4))) float f32x4;

union b8u { int i[4]; bf16x8 v; };
union fiu { float f; unsigned u; };

// fp32 -> bf16 RNE (prep only)
__device__ __forceinline__ short f2bf_rne(float f) {
    fiu v; v.f = f;
    unsigned r = v.u + 0x7fffu + ((v.u >> 16) & 1u);
    return (short)(r >> 16);
}

// Prep: cbbf = bf16(codebook), cbn[e] = -0.5*||cb_e||^2, zero loss slot.
__global__ void vq_prep(const float* __restrict__ cb,
                        short* __restrict__ cbbf,
                        float* __restrict__ cbn,
                        float* __restrict__ loss_slot) {
    int e = blockIdx.x * blockDim.x + threadIdx.x;
    if (e == 0) *loss_slot = 0.0f;
    if (e < NUM_EMB) {
        float s = 0.0f;
#pragma unroll
        for (int c = 0; c < CHANNELS; ++c) {
            float v = cb[e * CHANNELS + c];
            cbbf[e * CHANNELS + c] = f2bf_rne(v);
            s = __builtin_fmaf(v, v, s);
        }
        cbn[e] = -0.5f * s;
    }
}

// R9 = R8 wave-split + "#pragma unroll 1" on the scan loop. R7/R8's VGPR-180
// blowup was NOT the manual prefetch: dropping the trip count 32->16 crossed
// the compiler's full-unroll threshold, hoisting all 32 B-loads. Pinning the
// loop restores R6's per-iteration shape (VGPR ~56) while keeping 8192 waves
// (32 waves/CU) for latency hiding.
__global__ __launch_bounds__(BLOCK) void vq_main(
    const float* __restrict__ x,
    const float* __restrict__ cb,
    const short* __restrict__ cbbf,
    const float* __restrict__ cbn,
    float* __restrict__ out,
    float* __restrict__ loss_slot) {
#pragma clang fp contract(off)
    __shared__ float pm[2][POSB];   // packed (score|511-e) max per half per position
    __shared__ float wsum[4];

    const int tid  = threadIdx.x;
    const int wave = tid >> 6, lane = tid & 63;
    const int q    = lane >> 4, col = lane & 15;
    const int posgrp = wave >> 1;          // which 64-position group
    const int half   = wave & 1;           // which codebook half

    const int blockPos = blockIdx.x * POSB;   // 128 | 32768 -> whole block same b
    const int b     = blockPos >> 15;
    const int sbase = blockPos & 32767;
    const float* xb = x + (size_t)b * (CHANNELS * SPATIAL);
    const int wposbase = sbase + posgrp * 64;

    // ---- A fragments: 64 positions = 4 M-tiles of 16; bf16 by truncation ----
    b8u A[4][2];
#pragma unroll
    for (int t = 0; t < 4; ++t) {
        const unsigned* pu = (const unsigned*)xb + (wposbase + t * 16 + col);
#pragma unroll
        for (int kh = 0; kh < 2; ++kh) {
#pragma unroll
            for (int jj = 0; jj < 4; ++jj) {
                unsigned u0 = pu[(size_t)(kh * 32 + q * 8 + 2 * jj + 0) * SPATIAL];
                unsigned u1 = pu[(size_t)(kh * 32 + q * 8 + 2 * jj + 1) * SPATIAL];
                A[t][kh].i[jj] = __builtin_amdgcn_perm(u1, u0, 0x07060302u);
            }
        }
    }

    // packed running max per (t, r): high 23 bits score, low 9 bits 511-e
    float m[4][4];
#pragma unroll
    for (int t = 0; t < 4; ++t)
#pragma unroll
        for (int r = 0; r < 4; ++r) m[t][r] = -3.4e38f;

    const unsigned MASK = 0xFFFFFE00u;
    const int halfBase = half * 256;

#pragma unroll 1
    for (int nt = 0; nt < 16; ++nt) {
        const int e0 = halfBase + nt * 16;
        // B[n=col][k=q*8+j]: entry row e0+col, contiguous bf16 from global (L2-hot)
        const short* brow = cbbf + (size_t)(e0 + col) * CHANNELS + q * 8;
        bf16x8 B0 = *(const bf16x8*)(brow);
        bf16x8 B1 = *(const bf16x8*)(brow + 32);
        float cn = cbn[e0 + col];
        f32x4 ci = {cn, cn, cn, cn};
        const unsigned enc = (unsigned)(511 - (e0 + col));
#pragma unroll
        for (int t = 0; t < 4; ++t) {
            f32x4 acc = __builtin_amdgcn_mfma_f32_16x16x32_bf16(A[t][0].v, B0, ci, 0, 0, 0);
            acc = __builtin_amdgcn_mfma_f32_16x16x32_bf16(A[t][1].v, B1, acc, 0, 0, 0);
#pragma unroll
            for (int r = 0; r < 4; ++r) {
                fiu p; p.f = acc[r];
                p.u = (p.u & MASK) | enc;        // v_and_or_b32
                m[t][r] = fmaxf(m[t][r], p.f);   // v_max_f32
            }
        }
    }

    // ---- cross-lane max per position (butterfly over the 16 cols) ----
#pragma unroll
    for (int t = 0; t < 4; ++t) {
#pragma unroll
        for (int r = 0; r < 4; ++r) {
            float v = m[t][r];
#pragma unroll
            for (int d = 1; d < 16; d <<= 1)
                v = fmaxf(v, __shfl_xor(v, d, 64));
            if (col == 0)
                pm[half][posgrp * 64 + t * 16 + q * 4 + r] = v;
        }
    }
    __syncthreads();   // halves merge across waves

    // ---- epilogue: 2 threads per position, 32 channels each ----
    const int chalf = tid >> 7;          // 0 or 1
    const int pos   = tid & 127;
    fiu pk; pk.f = fmaxf(pm[0][pos], pm[1][pos]);
    const int bidx = 511 - (int)(pk.u & 511u);

    const float* qrow = cb + (size_t)bidx * CHANNELS + chalf * 32;
    const float* px = xb + (sbase + pos) + (size_t)(chalf * 32) * SPATIAL;
    float* op = out + (size_t)b * (CHANNELS * SPATIAL) + (sbase + pos)
                    + (size_t)(chalf * 32) * SPATIAL;
    float lsum = 0.0f;
#pragma unroll
    for (int c = 0; c < 32; ++c) {
        float xv = px[(size_t)c * SPATIAL];
        float t2 = qrow[c] - xv;
        op[(size_t)c * SPATIAL] = xv + t2;
        lsum = __builtin_fmaf(t2, t2, lsum);
    }

    // block loss reduction -> one atomic
#pragma unroll
    for (int off = 32; off > 0; off >>= 1) lsum += __shfl_down(lsum, off, 64);
    if (lane == 0) wsum[wave] = lsum;
    __syncthreads();
    if (tid == 0) {
        float bs = (wsum[0] + wsum[1]) + (wsum[2] + wsum[3]);
        atomicAdd(loss_slot, bs * LOSS_SCALE);
    }
}

extern "C" void kernel_launch(void* const* d_in, const int* in_sizes, int n_in,
                              void* d_out, int out_size, void* d_ws, size_t ws_size,
                              hipStream_t stream) {
    const float* x  = (const float*)d_in[0];
    const float* cb = (const float*)d_in[1];
    float* out = (float*)d_out;
    short* cbbf = (short*)d_ws;                        // 512*64 bf16 = 64 KB
    float* cbn  = (float*)(cbbf + NUM_EMB * CHANNELS); // 512 floats
    float* loss_slot = out + OUT_ELEMS;

    vq_prep<<<2, 256, 0, stream>>>(cb, cbbf, cbn, loss_slot);
    vq_main<<<NPOS / POSB, BLOCK, 0, stream>>>(x, cb, cbbf, cbn, out, loss_slot);
}

// Round 10
// 157.919 us; speedup vs baseline: 1.2598x; 1.0474x over previous
//
#include <hip/hip_runtime.h>
#include <cstdint>
#include <cstddef>

// x (B=8, C=64, S=32768) fp32; codebook (512, 64) fp32.
#define SPATIAL   32768
#define CHANNELS  64
#define NUM_EMB   512
#define NPOS      262144
#define OUT_ELEMS 16777216
#define BLOCK     1024           // 16 waves; block covers 1024 consecutive positions
#define POSB      1024           // -> 4 KB contiguous chunk per channel (DRAM row)
#define LOSS_SCALE (1.25f / 16777216.0f)

typedef __attribute__((ext_vector_type(8))) short bf16x8;
typedef __attribute__((ext_vector_type(4))) float f32x4;

union b8u { int i[4]; bf16x8 v; };
union fiu { float f; unsigned u; };

// fp32 -> bf16 RNE (prep only)
__device__ __forceinline__ short f2bf_rne(float f) {
    fiu v; v.f = f;
    unsigned r = v.u + 0x7fffu + ((v.u >> 16) & 1u);
    return (short)(r >> 16);
}

// Prep: cbbf = bf16(codebook), cbn[e] = -0.5*||cb_e||^2, zero loss slot.
__global__ void vq_prep(const float* __restrict__ cb,
                        short* __restrict__ cbbf,
                        float* __restrict__ cbn,
                        float* __restrict__ loss_slot) {
    int e = blockIdx.x * blockDim.x + threadIdx.x;
    if (e == 0) *loss_slot = 0.0f;
    if (e < NUM_EMB) {
        float s = 0.0f;
#pragma unroll
        for (int c = 0; c < CHANNELS; ++c) {
            float v = cb[e * CHANNELS + c];
            cbbf[e * CHANNELS + c] = f2bf_rne(v);
            s = __builtin_fmaf(v, v, s);
        }
        cbn[e] = -0.5f * s;
    }
}

// R10: DRAM-page-locality attack. R6/R9 sat at ~1.7-2.0 TB/s effective HBM
// (vs 6.3 dense) because x reads / out writes are 64B segments at 128KB
// channel stride with only 512B-1KB per-channel chunks per block -> row
// thrash. Block = 1024 consecutive positions (4KB/channel = full DRAM row),
// 16 waves issue together -> row-hit streaks. Wave-split removed (R9: no
// benefit); no mid-kernel barrier. Scan keeps R9's unroll-1 shape (VGPR~56).
__global__ __launch_bounds__(BLOCK) void vq_main(
    const float* __restrict__ x,
    const float* __restrict__ cb,
    const short* __restrict__ cbbf,
    const float* __restrict__ cbn,
    float* __restrict__ out,
    float* __restrict__ loss_slot) {
#pragma clang fp contract(off)
    __shared__ int   cand[POSB];    // 4 KB: winner index per position
    __shared__ float wsum[16];

    const int tid  = threadIdx.x;
    const int wave = tid >> 6, lane = tid & 63;
    const int q    = lane >> 4, col = lane & 15;

    const int blockPos = blockIdx.x * POSB;   // 1024 | 32768 -> whole block same b
    const int b     = blockPos >> 15;
    const int sbase = blockPos & 32767;
    const float* xb = x + (size_t)b * (CHANNELS * SPATIAL);
    const int wposbase = sbase + wave * 64;

    // ---- A fragments: wave covers 64 positions = 4 M-tiles; bf16 truncation ----
    b8u A[4][2];
#pragma unroll
    for (int t = 0; t < 4; ++t) {
        const unsigned* pu = (const unsigned*)xb + (wposbase + t * 16 + col);
#pragma unroll
        for (int kh = 0; kh < 2; ++kh) {
#pragma unroll
            for (int jj = 0; jj < 4; ++jj) {
                unsigned u0 = pu[(size_t)(kh * 32 + q * 8 + 2 * jj + 0) * SPATIAL];
                unsigned u1 = pu[(size_t)(kh * 32 + q * 8 + 2 * jj + 1) * SPATIAL];
                A[t][kh].i[jj] = __builtin_amdgcn_perm(u1, u0, 0x07060302u);
            }
        }
    }

    // packed running max per (t, r): high 23 bits score, low 9 bits 511-e
    float m[4][4];
#pragma unroll
    for (int t = 0; t < 4; ++t)
#pragma unroll
        for (int r = 0; r < 4; ++r) m[t][r] = -3.4e38f;

    const unsigned MASK = 0xFFFFFE00u;

#pragma unroll 1
    for (int nt = 0; nt < 32; ++nt) {
        const int e0 = nt * 16;
        // B[n=col][k=q*8+j]: entry row e0+col, contiguous bf16 (L2-hot)
        const short* brow = cbbf + (size_t)(e0 + col) * CHANNELS + q * 8;
        bf16x8 B0 = *(const bf16x8*)(brow);
        bf16x8 B1 = *(const bf16x8*)(brow + 32);
        float cn = cbn[e0 + col];
        f32x4 ci = {cn, cn, cn, cn};
        const unsigned enc = (unsigned)(511 - (e0 + col));
#pragma unroll
        for (int t = 0; t < 4; ++t) {
            f32x4 acc = __builtin_amdgcn_mfma_f32_16x16x32_bf16(A[t][0].v, B0, ci, 0, 0, 0);
            acc = __builtin_amdgcn_mfma_f32_16x16x32_bf16(A[t][1].v, B1, acc, 0, 0, 0);
#pragma unroll
            for (int r = 0; r < 4; ++r) {
                fiu p; p.f = acc[r];
                p.u = (p.u & MASK) | enc;        // v_and_or_b32
                m[t][r] = fmaxf(m[t][r], p.f);   // v_max_f32
            }
        }
    }

    // ---- cross-lane max per position (butterfly over the 16 cols) ----
#pragma unroll
    for (int t = 0; t < 4; ++t) {
#pragma unroll
        for (int r = 0; r < 4; ++r) {
            float v = m[t][r];
#pragma unroll
            for (int d = 1; d < 16; d <<= 1)
                v = fmaxf(v, __shfl_xor(v, d, 64));
            if (col == 0) {
                fiu p; p.f = v;
                cand[wave * 64 + t * 16 + q * 4 + r] = 511 - (int)(p.u & 511u);
            }
        }
    }
    // cand written and read by the same wave -> intra-wave LDS order, no barrier

    // ---- epilogue: 1 thread per position, 64 channels ----
    const int bidx = cand[tid];
    const float* qrow = cb + (size_t)bidx * CHANNELS;
    const float* px = xb + (sbase + tid);
    float* op = out + (size_t)b * (CHANNELS * SPATIAL) + (sbase + tid);
    float lsum = 0.0f;
#pragma unroll
    for (int c = 0; c < CHANNELS; ++c) {
        float xv = px[(size_t)c * SPATIAL];
        float t2 = qrow[c] - xv;
        op[(size_t)c * SPATIAL] = xv + t2;
        lsum = __builtin_fmaf(t2, t2, lsum);
    }

    // block loss reduction -> one atomic
#pragma unroll
    for (int off = 32; off > 0; off >>= 1) lsum += __shfl_down(lsum, off, 64);
    if (lane == 0) wsum[wave] = lsum;
    __syncthreads();
    if (tid == 0) {
        float bs = 0.0f;
#pragma unroll
        for (int w = 0; w < 16; ++w) bs += wsum[w];
        atomicAdd(loss_slot, bs * LOSS_SCALE);
    }
}

extern "C" void kernel_launch(void* const* d_in, const int* in_sizes, int n_in,
                              void* d_out, int out_size, void* d_ws, size_t ws_size,
                              hipStream_t stream) {
    const float* x  = (const float*)d_in[0];
    const float* cb = (const float*)d_in[1];
    float* out = (float*)d_out;
    short* cbbf = (short*)d_ws;                        // 512*64 bf16 = 64 KB
    float* cbn  = (float*)(cbbf + NUM_EMB * CHANNELS); // 512 floats
    float* loss_slot = out + OUT_ELEMS;

    vq_prep<<<2, 256, 0, stream>>>(cb, cbbf, cbn, loss_slot);
    vq_main<<<NPOS / POSB, BLOCK, 0, stream>>>(x, cb, cbbf, cbn, out, loss_slot);
}